// Round 4
// baseline (1114.705 us; speedup 1.0000x reference)
//
#include <hip/hip_runtime.h>

typedef _Float16 f16;
typedef _Float16 f16x4 __attribute__((ext_vector_type(4)));
typedef _Float16 f16x8 __attribute__((ext_vector_type(8)));
typedef float f32x4 __attribute__((ext_vector_type(4)));

// async global->LDS, 16B per lane; LDS dest = wave-uniform base + lane*16
#define LOADLDS16(gp, lp)                                                     \
  __builtin_amdgcn_global_load_lds(                                           \
      (const __attribute__((address_space(1))) void*)(gp),                    \
      (__attribute__((address_space(3))) void*)(lp), 16, 0, 0)

// ---------------------------------------------------------------------------
// Elementwise cast f32 -> f16 (vectorized)
// ---------------------------------------------------------------------------
__global__ __launch_bounds__(256) void k_cast(const float* __restrict__ x,
                                              f16* __restrict__ y, int n4) {
  int i = blockIdx.x * 256 + threadIdx.x;
  if (i >= n4) return;
  float4 v = reinterpret_cast<const float4*>(x)[i];
  f16x4 o;
  o[0] = (f16)v.x; o[1] = (f16)v.y; o[2] = (f16)v.z; o[3] = (f16)v.w;
  reinterpret_cast<f16x4*>(y)[i] = o;
}

// ---------------------------------------------------------------------------
// Cast + transpose weights: W[1024][1024] f32 -> Wt[N][K] f16  (Wt[n][k]=W[k][n])
// ---------------------------------------------------------------------------
__global__ __launch_bounds__(256) void k_castw_t(
    const float* __restrict__ w0, const float* __restrict__ w1,
    const float* __restrict__ w2, const float* __restrict__ w3,
    f16* __restrict__ o0, f16* __restrict__ o1, f16* __restrict__ o2,
    f16* __restrict__ o3) {
  const float* W;
  f16* O;
  switch (blockIdx.z) {
    case 0: W = w0; O = o0; break;
    case 1: W = w1; O = o1; break;
    case 2: W = w2; O = o2; break;
    default: W = w3; O = o3; break;
  }
  __shared__ f16 T[64][72];
  const int tid = threadIdx.x;
  const int r0 = blockIdx.y * 64, c0 = blockIdx.x * 64;
#pragma unroll
  for (int i = 0; i < 4; ++i) {
    int c = i * 256 + tid;
    int row = c >> 4, col = (c & 15) * 4;
    float4 v = *reinterpret_cast<const float4*>(W + (size_t)(r0 + row) * 1024 + c0 + col);
    T[col + 0][row] = (f16)v.x;
    T[col + 1][row] = (f16)v.y;
    T[col + 2][row] = (f16)v.z;
    T[col + 3][row] = (f16)v.w;
  }
  __syncthreads();
#pragma unroll
  for (int i = 0; i < 2; ++i) {
    int c = i * 256 + tid;
    int cc = c >> 3, ro = (c & 7) * 8;
    f16x8 v;
#pragma unroll
    for (int j = 0; j < 8; ++j) v[j] = T[cc][ro + j];
    *reinterpret_cast<f16x8*>(O + (size_t)(c0 + cc) * 1024 + r0 + ro) = v;
  }
}

// ---------------------------------------------------------------------------
// Fused QKV projection: C[4096, 3072] where cols 0-1023 = Xq@Wqt, 1024-2047 =
// Xkv@Wkt, 2048-3071 = Xkv@Wvt. m97 structure: BM=BN=128, BK=64, 4 waves,
// 4x4 acc/wave, global_load_lds x16B. Bt = [Wqt|Wkt|Wvt] rows (contiguous ws).
// Epilogue scatters to qbuf/kbuf/vbuf head-layout planes (plane stride 4M f16).
// ---------------------------------------------------------------------------
__global__ __launch_bounds__(256) void k_gemm_qkv(const f16* __restrict__ Xq,
                                                  const f16* __restrict__ Xkv,
                                                  const f16* __restrict__ Bt,
                                                  f16* __restrict__ outp) {
  __shared__ f16 As[128 * 64];  // 16 KB
  __shared__ f16 Bs[128 * 64];  // 16 KB
  const int tid = threadIdx.x;
  const int w = tid >> 6, l = tid & 63;
  const int lr = l & 15, lq = l >> 4;
  const int m0 = blockIdx.y * 128, n0 = blockIdx.x * 128;
  const f16* A = (n0 < 1024) ? Xq : Xkv;
  const int wr = (w >> 1) * 64, wc = (w & 1) * 64;
  const int K = 1024;
  f32x4 acc[4][4] = {};
  for (int kt = 0; kt < K; kt += 64) {
#pragma unroll
    for (int i = 0; i < 4; ++i) {
      int c = (i * 4 + w) * 64 + l;
      LOADLDS16(A + (size_t)(m0 + (c >> 3)) * K + kt + (c & 7) * 8,
                As + (size_t)(i * 4 + w) * 512);
      LOADLDS16(Bt + (size_t)(n0 + (c >> 3)) * K + kt + (c & 7) * 8,
                Bs + (size_t)(i * 4 + w) * 512);
    }
    __syncthreads();
#pragma unroll
    for (int kk = 0; kk < 2; ++kk) {
      f16x8 af[4], bf[4];
#pragma unroll
      for (int m = 0; m < 4; ++m)
        af[m] = *reinterpret_cast<const f16x8*>(As + (wr + m * 16 + lr) * 64 + kk * 32 + lq * 8);
#pragma unroll
      for (int n = 0; n < 4; ++n)
        bf[n] = *reinterpret_cast<const f16x8*>(Bs + (wc + n * 16 + lr) * 64 + kk * 32 + lq * 8);
#pragma unroll
      for (int m = 0; m < 4; ++m)
#pragma unroll
        for (int n = 0; n < 4; ++n)
          acc[m][n] = __builtin_amdgcn_mfma_f32_16x16x32_f16(af[m], bf[n], acc[m][n], 0, 0, 0);
    }
    __syncthreads();
  }
#pragma unroll
  for (int m = 0; m < 4; ++m)
#pragma unroll
    for (int n = 0; n < 4; ++n)
#pragma unroll
      for (int r = 0; r < 4; ++r) {
        int row = m0 + wr + m * 16 + lq * 4 + r;
        int col = n0 + wc + n * 16 + lr;
        int b = row >> 10, s = row & 1023;
        int plane = col >> 10, cc = col & 1023;
        int h = cc >> 6, dh = cc & 63;
        outp[(size_t)plane * 4194304 +
             (((size_t)(b * 16 + h)) * 1024 + s) * 64 + dh] = (f16)acc[m][n][r];
      }
}

// ---------------------------------------------------------------------------
// Output GEMM: C[M,N] f32 = A[M,K] @ Bt[N,K]^T. BM=64, BN=128 (512 blocks).
// ---------------------------------------------------------------------------
__global__ __launch_bounds__(256) void k_gemm_o(const f16* __restrict__ A,
                                                const f16* __restrict__ Bt,
                                                float* __restrict__ out, int M,
                                                int N, int K) {
  __shared__ f16 As[64 * 64];
  __shared__ f16 Bs[128 * 64];
  const int tid = threadIdx.x;
  const int w = tid >> 6, l = tid & 63;
  const int lr = l & 15, lq = l >> 4;
  const int m0 = blockIdx.y * 64, n0 = blockIdx.x * 128;
  const int wr = (w >> 1) * 32, wc = (w & 1) * 64;
  f32x4 acc[2][4] = {};
  for (int kt = 0; kt < K; kt += 64) {
#pragma unroll
    for (int i = 0; i < 2; ++i) {
      int c = (i * 4 + w) * 64 + l;
      LOADLDS16(A + (size_t)(m0 + (c >> 3)) * K + kt + (c & 7) * 8,
                As + (size_t)(i * 4 + w) * 512);
    }
#pragma unroll
    for (int i = 0; i < 4; ++i) {
      int c = (i * 4 + w) * 64 + l;
      LOADLDS16(Bt + (size_t)(n0 + (c >> 3)) * K + kt + (c & 7) * 8,
                Bs + (size_t)(i * 4 + w) * 512);
    }
    __syncthreads();
#pragma unroll
    for (int kk = 0; kk < 2; ++kk) {
      f16x8 af[2], bf[4];
#pragma unroll
      for (int m = 0; m < 2; ++m)
        af[m] = *reinterpret_cast<const f16x8*>(As + (wr + m * 16 + lr) * 64 + kk * 32 + lq * 8);
#pragma unroll
      for (int n = 0; n < 4; ++n)
        bf[n] = *reinterpret_cast<const f16x8*>(Bs + (wc + n * 16 + lr) * 64 + kk * 32 + lq * 8);
#pragma unroll
      for (int m = 0; m < 2; ++m)
#pragma unroll
        for (int n = 0; n < 4; ++n)
          acc[m][n] = __builtin_amdgcn_mfma_f32_16x16x32_f16(af[m], bf[n], acc[m][n], 0, 0, 0);
    }
    __syncthreads();
  }
#pragma unroll
  for (int m = 0; m < 2; ++m)
#pragma unroll
    for (int n = 0; n < 4; ++n)
#pragma unroll
      for (int r = 0; r < 4; ++r) {
        int row = m0 + wr + m * 16 + lq * 4 + r;
        int col = n0 + wc + n * 16 + lr;
        out[(size_t)row * N + col] = acc[m][n][r];
      }
}

// ---------------------------------------------------------------------------
// V transpose per head: vb[bh][1024][64] -> vtb[bh][64][1024]
// ---------------------------------------------------------------------------
__global__ __launch_bounds__(256) void k_vtrans(const f16* __restrict__ vb,
                                                f16* __restrict__ vtb) {
  const int bh = blockIdx.y, s0 = blockIdx.x * 64;
  __shared__ f16 T[64][72];
  const int tid = threadIdx.x;
  const f16* src = vb + (size_t)bh * 1024 * 64;
#pragma unroll
  for (int i = 0; i < 2; ++i) {
    int c = i * 256 + tid;
    int row = c >> 3, co = (c & 7) * 8;
    f16x8 v = *reinterpret_cast<const f16x8*>(src + (size_t)(s0 + row) * 64 + co);
#pragma unroll
    for (int j = 0; j < 8; ++j) T[co + j][row] = v[j];
  }
  __syncthreads();
  f16* dst = vtb + (size_t)bh * 64 * 1024;
#pragma unroll
  for (int i = 0; i < 2; ++i) {
    int c = i * 256 + tid;
    int dh = c >> 3, so = (c & 7) * 8;
    f16x8 v;
#pragma unroll
    for (int j = 0; j < 8; ++j) v[j] = T[dh][so + j];
    *reinterpret_cast<f16x8*>(dst + (size_t)dh * 1024 + s0 + so) = v;
  }
}

// ---------------------------------------------------------------------------
// Fused flash attention (T5: scores = QK^T + bias, no 1/sqrt scale).
// 4 waves x 16 q-rows; KV tiles of 64, double-buffered, XOR-swizzled LDS.
// XCD-chunked grid (each XCD owns 2 heads; 4 batches of a (h,qt) tile co-run
// on the SAME XCD -> bias fetched once per XCD).
// Pipelining: K/V reg-prefetch (depth 1) + bias reg-prefetch (depth 1,
// ping-pong bA/bB), pinned with sched_barrier(0) so the scheduler cannot
// sink the loads to their uses (round-2 failure: VGPR=64 proved it did).
// ---------------------------------------------------------------------------
__global__ __launch_bounds__(256, 4) void k_attn(const f16* __restrict__ qb,
                                                 const f16* __restrict__ kb,
                                                 const f16* __restrict__ vtb,
                                                 const float* __restrict__ bias,
                                                 f16* __restrict__ ctx) {
  const int bid = blockIdx.x;
  const int ord = (bid & 7) * 128 + (bid >> 3);
  const int h = ord >> 6, qt = (ord >> 2) & 15, b = ord & 3;
  const int bh = b * 16 + h;
  const int q0 = qt * 64;
  const int tid = threadIdx.x, w = tid >> 6, l = tid & 63;
  const int lr = l & 15, lq = l >> 4;

  // linear [64][64] f16 tiles, XOR-swizzled: elem = row*64 + (col ^ ((row&7)<<3))
  __shared__ f16 Ks[2][4096];
  __shared__ f16 Vs[2][4096];
  __shared__ f16 Ps[4][1024];  // per-wave [16][64], same swizzle

  const f16* qp = qb + ((size_t)bh * 1024 + q0 + w * 16 + lr) * 64 + lq * 8;
  f16x8 qf0 = *reinterpret_cast<const f16x8*>(qp);
  f16x8 qf1 = *reinterpret_cast<const f16x8*>(qp + 32);

  f32x4 O[4] = {};
  float mrun[4], lrun[4];
#pragma unroll
  for (int r = 0; r < 4; ++r) { mrun[r] = -3.0e38f; lrun[r] = 0.f; }

  const f16* kbase = kb + (size_t)bh * 1024 * 64;
  const f16* vbase = vtb + (size_t)bh * 64 * 1024;
  const float* bbase = bias + ((size_t)h * 1024 + q0 + w * 16) * 1024;

  const int row0 = tid >> 3, co = (tid & 7) * 8;

  float bA[16], bB[16];

  // ---- prologue: stage KV tile 0 into LDS, bias tile 0 into bA ----
#pragma unroll
  for (int i = 0; i < 2; ++i) {
    int row = row0 + i * 32;
    int sw = row * 64 + (co ^ ((row & 7) << 3));
    *reinterpret_cast<f16x8*>(&Ks[0][sw]) =
        *reinterpret_cast<const f16x8*>(kbase + (size_t)row * 64 + co);
    *reinterpret_cast<f16x8*>(&Vs[0][sw]) =
        *reinterpret_cast<const f16x8*>(vbase + (size_t)row * 1024 + co);
  }
#pragma unroll
  for (int c = 0; c < 4; ++c)
#pragma unroll
    for (int r = 0; r < 4; ++r)
      bA[c * 4 + r] = bbase[(size_t)(lq * 4 + r) * 1024 + c * 16 + lr];
  __syncthreads();

  auto body = [&](int it, int cur, float (&bc)[16], float (&bn)[16]) {
    // ---- (A) prefetch next K/V tile + next bias tile into regs ----
    f16x8 kreg[2], vreg[2];
    if (it < 15) {
      const f16* kn = kbase + (size_t)(it + 1) * 64 * 64;
      const f16* vn = vbase + (size_t)(it + 1) * 64;
#pragma unroll
      for (int i = 0; i < 2; ++i) {
        int row = row0 + i * 32;
        kreg[i] = *reinterpret_cast<const f16x8*>(kn + (size_t)row * 64 + co);
        vreg[i] = *reinterpret_cast<const f16x8*>(vn + (size_t)row * 1024 + co);
      }
      const float* bp = bbase + (it + 1) * 64;
#pragma unroll
      for (int c = 0; c < 4; ++c)
#pragma unroll
        for (int r = 0; r < 4; ++r)
          bn[c * 4 + r] = bp[(size_t)(lq * 4 + r) * 1024 + c * 16 + lr];
    }
    // pin: loads above may NOT sink below this point
    __builtin_amdgcn_sched_barrier(0);

    // ---- (B) S = Q K^T ----
    f32x4 S[4] = {};
    __builtin_amdgcn_s_setprio(1);
#pragma unroll
    for (int c = 0; c < 4; ++c) {
      int row = c * 16 + lr;
      int base = row * 64, s8 = (row & 7) << 3;
      f16x8 kf0 = *reinterpret_cast<const f16x8*>(&Ks[cur][base + ((lq * 8) ^ s8)]);
      f16x8 kf1 = *reinterpret_cast<const f16x8*>(&Ks[cur][base + ((32 + lq * 8) ^ s8)]);
      S[c] = __builtin_amdgcn_mfma_f32_16x16x32_f16(qf0, kf0, S[c], 0, 0, 0);
      S[c] = __builtin_amdgcn_mfma_f32_16x16x32_f16(qf1, kf1, S[c], 0, 0, 0);
    }
    __builtin_amdgcn_s_setprio(0);

    // ---- + position bias (prefetched LAST iteration -> full-body cover) ----
#pragma unroll
    for (int c = 0; c < 4; ++c)
#pragma unroll
      for (int r = 0; r < 4; ++r) S[c][r] += bc[c * 4 + r];

    // ---- online softmax (row = lq*4+r; reduce over 16 lanes of lr) ----
    float tmax[4];
#pragma unroll
    for (int r = 0; r < 4; ++r)
      tmax[r] = fmaxf(fmaxf(S[0][r], S[1][r]), fmaxf(S[2][r], S[3][r]));
#pragma unroll
    for (int msk = 1; msk <= 8; msk <<= 1)
#pragma unroll
      for (int r = 0; r < 4; ++r)
        tmax[r] = fmaxf(tmax[r], __shfl_xor(tmax[r], msk, 64));
    float scale[4], rsum[4];
#pragma unroll
    for (int r = 0; r < 4; ++r) {
      float mnew = fmaxf(mrun[r], tmax[r]);
      scale[r] = __expf(mrun[r] - mnew);
      mrun[r] = mnew;
      rsum[r] = 0.f;
    }
#pragma unroll
    for (int c = 0; c < 4; ++c)
#pragma unroll
      for (int r = 0; r < 4; ++r) {
        float p = __expf(S[c][r] - mrun[r]);
        S[c][r] = p;
        rsum[r] += p;
      }
#pragma unroll
    for (int msk = 1; msk <= 8; msk <<= 1)
#pragma unroll
      for (int r = 0; r < 4; ++r) rsum[r] += __shfl_xor(rsum[r], msk, 64);
#pragma unroll
    for (int r = 0; r < 4; ++r) lrun[r] = lrun[r] * scale[r] + rsum[r];

    // ---- rescale O, spill P (wave-private; lgkmcnt orders round-trip) ----
#pragma unroll
    for (int c = 0; c < 4; ++c)
#pragma unroll
      for (int r = 0; r < 4; ++r) {
        O[c][r] *= scale[r];
        int prow = lq * 4 + r;
        Ps[w][prow * 64 + ((c * 16 + lr) ^ ((prow & 7) << 3))] = (f16)S[c][r];
      }

    // ---- O += P @ V ----
    {
      int s8p = (lr & 7) << 3;
      f16x8 pa0 = *reinterpret_cast<const f16x8*>(&Ps[w][lr * 64 + ((lq * 8) ^ s8p)]);
      f16x8 pa1 = *reinterpret_cast<const f16x8*>(&Ps[w][lr * 64 + ((32 + lq * 8) ^ s8p)]);
      __builtin_amdgcn_s_setprio(1);
#pragma unroll
      for (int c = 0; c < 4; ++c) {
        int row = c * 16 + lr;
        int base = row * 64, s8 = (row & 7) << 3;
        f16x8 vf0 = *reinterpret_cast<const f16x8*>(&Vs[cur][base + ((lq * 8) ^ s8)]);
        f16x8 vf1 = *reinterpret_cast<const f16x8*>(&Vs[cur][base + ((32 + lq * 8) ^ s8)]);
        O[c] = __builtin_amdgcn_mfma_f32_16x16x32_f16(pa0, vf0, O[c], 0, 0, 0);
        O[c] = __builtin_amdgcn_mfma_f32_16x16x32_f16(pa1, vf1, O[c], 0, 0, 0);
      }
      __builtin_amdgcn_s_setprio(0);
    }

    // ---- commit prefetched K/V tile to the other buffer ----
    if (it < 15) {
#pragma unroll
      for (int i = 0; i < 2; ++i) {
        int row = row0 + i * 32;
        int sw = row * 64 + (co ^ ((row & 7) << 3));
        *reinterpret_cast<f16x8*>(&Ks[cur ^ 1][sw]) = kreg[i];
        *reinterpret_cast<f16x8*>(&Vs[cur ^ 1][sw]) = vreg[i];
      }
    }
    __syncthreads();
  };

#pragma unroll 1
  for (int ith = 0; ith < 8; ++ith) {
    body(2 * ith, 0, bA, bB);
    body(2 * ith + 1, 1, bB, bA);
  }

  // ---- epilogue: ctx[b][q][h*64+dh] f16 ----
#pragma unroll
  for (int c = 0; c < 4; ++c)
#pragma unroll
    for (int r = 0; r < 4; ++r) {
      float o = O[c][r] / lrun[r];
      int row = q0 + w * 16 + lq * 4 + r;
      ctx[((size_t)b * 1024 + row) * 1024 + h * 64 + c * 16 + lr] = (f16)o;
    }
}

// ---------------------------------------------------------------------------
extern "C" void kernel_launch(void* const* d_in, const int* in_sizes, int n_in,
                              void* d_out, int out_size, void* d_ws,
                              size_t ws_size, hipStream_t stream) {
  const float* input_ids = (const float*)d_in[0];
  const float* enc = (const float*)d_in[1];
  const float* bias = (const float*)d_in[2];
  const float* Wq = (const float*)d_in[3];
  const float* Wk = (const float*)d_in[4];
  const float* Wv = (const float*)d_in[5];
  const float* Wo = (const float*)d_in[6];

  char* ws = (char*)d_ws;
  const size_t MB = 1024 * 1024;
  f16* Xq  = (f16*)(ws + 0 * MB);   // 8 MB; dead after QKV-proj -> reused as ctx
  f16* Xkv = (f16*)(ws + 8 * MB);   // 8 MB; dead after QKV-proj -> reused as vtb
  f16* Wqt = (f16*)(ws + 16 * MB);  // 2 MB each; Wqt|Wkt|Wvt contiguous = [3072][1024]
  f16* Wkt = (f16*)(ws + 18 * MB);
  f16* Wvt = (f16*)(ws + 20 * MB);
  f16* Wot = (f16*)(ws + 22 * MB);
  f16* qbuf = (f16*)(ws + 24 * MB); // 8 MB [bh][s][dh]; kbuf/vbuf planes follow
  f16* kbuf = (f16*)(ws + 32 * MB);
  f16* vbuf = (f16*)(ws + 40 * MB);
  f16* vtb = Xkv;   // [bh][dh][sk]
  f16* ctxb = Xq;   // [4096][1024]

  k_cast<<<4096, 256, 0, stream>>>(input_ids, Xq, 1048576);
  k_cast<<<4096, 256, 0, stream>>>(enc, Xkv, 1048576);
  k_castw_t<<<dim3(16, 16, 4), 256, 0, stream>>>(Wq, Wk, Wv, Wo, Wqt, Wkt, Wvt, Wot);

  // fused Q+K+V projection: N=3072 over [Wqt|Wkt|Wvt], per-block A select
  k_gemm_qkv<<<dim3(24, 32), 256, 0, stream>>>(Xq, Xkv, Wqt, qbuf);

  k_vtrans<<<dim3(16, 64), 256, 0, stream>>>(vbuf, vtb);

  k_attn<<<1024, 256, 0, stream>>>(qbuf, kbuf, vtb, bias, ctxb);

  k_gemm_o<<<dim3(8, 64), 256, 0, stream>>>(ctxb, Wot, (float*)d_out, 4096, 1024, 1024);
}

// Round 5
// 189.014 us; speedup vs baseline: 5.8975x; 5.8975x over previous
//
#include <hip/hip_runtime.h>

typedef _Float16 f16;
typedef _Float16 f16x4 __attribute__((ext_vector_type(4)));
typedef _Float16 f16x8 __attribute__((ext_vector_type(8)));
typedef float f32x4 __attribute__((ext_vector_type(4)));

// async global->LDS, 16B per lane; LDS dest = wave-uniform base + lane*16
#define LOADLDS16(gp, lp)                                                     \
  __builtin_amdgcn_global_load_lds(                                           \
      (const __attribute__((address_space(1))) void*)(gp),                    \
      (__attribute__((address_space(3))) void*)(lp), 16, 0, 0)

// ---------------------------------------------------------------------------
// Elementwise cast f32 -> f16 (vectorized)
// ---------------------------------------------------------------------------
__global__ __launch_bounds__(256) void k_cast(const float* __restrict__ x,
                                              f16* __restrict__ y, int n4) {
  int i = blockIdx.x * 256 + threadIdx.x;
  if (i >= n4) return;
  float4 v = reinterpret_cast<const float4*>(x)[i];
  f16x4 o;
  o[0] = (f16)v.x; o[1] = (f16)v.y; o[2] = (f16)v.z; o[3] = (f16)v.w;
  reinterpret_cast<f16x4*>(y)[i] = o;
}

// ---------------------------------------------------------------------------
// Cast + transpose weights: W[1024][1024] f32 -> Wt[N][K] f16  (Wt[n][k]=W[k][n])
// ---------------------------------------------------------------------------
__global__ __launch_bounds__(256) void k_castw_t(
    const float* __restrict__ w0, const float* __restrict__ w1,
    const float* __restrict__ w2, const float* __restrict__ w3,
    f16* __restrict__ o0, f16* __restrict__ o1, f16* __restrict__ o2,
    f16* __restrict__ o3) {
  const float* W;
  f16* O;
  switch (blockIdx.z) {
    case 0: W = w0; O = o0; break;
    case 1: W = w1; O = o1; break;
    case 2: W = w2; O = o2; break;
    default: W = w3; O = o3; break;
  }
  __shared__ f16 T[64][72];
  const int tid = threadIdx.x;
  const int r0 = blockIdx.y * 64, c0 = blockIdx.x * 64;
#pragma unroll
  for (int i = 0; i < 4; ++i) {
    int c = i * 256 + tid;
    int row = c >> 4, col = (c & 15) * 4;
    float4 v = *reinterpret_cast<const float4*>(W + (size_t)(r0 + row) * 1024 + c0 + col);
    T[col + 0][row] = (f16)v.x;
    T[col + 1][row] = (f16)v.y;
    T[col + 2][row] = (f16)v.z;
    T[col + 3][row] = (f16)v.w;
  }
  __syncthreads();
#pragma unroll
  for (int i = 0; i < 2; ++i) {
    int c = i * 256 + tid;
    int cc = c >> 3, ro = (c & 7) * 8;
    f16x8 v;
#pragma unroll
    for (int j = 0; j < 8; ++j) v[j] = T[cc][ro + j];
    *reinterpret_cast<f16x8*>(O + (size_t)(c0 + cc) * 1024 + r0 + ro) = v;
  }
}

// ---------------------------------------------------------------------------
// Fused QKV projection: C[4096, 3072] where cols 0-1023 = Xq@Wqt, 1024-2047 =
// Xkv@Wkt, 2048-3071 = Xkv@Wvt. m97 structure: BM=BN=128, BK=64, 4 waves,
// 4x4 acc/wave, global_load_lds x16B. Bt = [Wqt|Wkt|Wvt] rows (contiguous ws).
// ---------------------------------------------------------------------------
__global__ __launch_bounds__(256) void k_gemm_qkv(const f16* __restrict__ Xq,
                                                  const f16* __restrict__ Xkv,
                                                  const f16* __restrict__ Bt,
                                                  f16* __restrict__ outp) {
  __shared__ f16 As[128 * 64];  // 16 KB
  __shared__ f16 Bs[128 * 64];  // 16 KB
  const int tid = threadIdx.x;
  const int w = tid >> 6, l = tid & 63;
  const int lr = l & 15, lq = l >> 4;
  const int m0 = blockIdx.y * 128, n0 = blockIdx.x * 128;
  const f16* A = (n0 < 1024) ? Xq : Xkv;
  const int wr = (w >> 1) * 64, wc = (w & 1) * 64;
  const int K = 1024;
  f32x4 acc[4][4] = {};
  for (int kt = 0; kt < K; kt += 64) {
#pragma unroll
    for (int i = 0; i < 4; ++i) {
      int c = (i * 4 + w) * 64 + l;
      LOADLDS16(A + (size_t)(m0 + (c >> 3)) * K + kt + (c & 7) * 8,
                As + (size_t)(i * 4 + w) * 512);
      LOADLDS16(Bt + (size_t)(n0 + (c >> 3)) * K + kt + (c & 7) * 8,
                Bs + (size_t)(i * 4 + w) * 512);
    }
    __syncthreads();
#pragma unroll
    for (int kk = 0; kk < 2; ++kk) {
      f16x8 af[4], bf[4];
#pragma unroll
      for (int m = 0; m < 4; ++m)
        af[m] = *reinterpret_cast<const f16x8*>(As + (wr + m * 16 + lr) * 64 + kk * 32 + lq * 8);
#pragma unroll
      for (int n = 0; n < 4; ++n)
        bf[n] = *reinterpret_cast<const f16x8*>(Bs + (wc + n * 16 + lr) * 64 + kk * 32 + lq * 8);
#pragma unroll
      for (int m = 0; m < 4; ++m)
#pragma unroll
        for (int n = 0; n < 4; ++n)
          acc[m][n] = __builtin_amdgcn_mfma_f32_16x16x32_f16(af[m], bf[n], acc[m][n], 0, 0, 0);
    }
    __syncthreads();
  }
#pragma unroll
  for (int m = 0; m < 4; ++m)
#pragma unroll
    for (int n = 0; n < 4; ++n)
#pragma unroll
      for (int r = 0; r < 4; ++r) {
        int row = m0 + wr + m * 16 + lq * 4 + r;
        int col = n0 + wc + n * 16 + lr;
        int b = row >> 10, s = row & 1023;
        int plane = col >> 10, cc = col & 1023;
        int h = cc >> 6, dh = cc & 63;
        outp[(size_t)plane * 4194304 +
             (((size_t)(b * 16 + h)) * 1024 + s) * 64 + dh] = (f16)acc[m][n][r];
      }
}

// ---------------------------------------------------------------------------
// Output GEMM: C[M,N] f32 = A[M,K] @ Bt[N,K]^T. BM=64, BN=128 (512 blocks).
// ---------------------------------------------------------------------------
__global__ __launch_bounds__(256) void k_gemm_o(const f16* __restrict__ A,
                                                const f16* __restrict__ Bt,
                                                float* __restrict__ out, int M,
                                                int N, int K) {
  __shared__ f16 As[64 * 64];
  __shared__ f16 Bs[128 * 64];
  const int tid = threadIdx.x;
  const int w = tid >> 6, l = tid & 63;
  const int lr = l & 15, lq = l >> 4;
  const int m0 = blockIdx.y * 64, n0 = blockIdx.x * 128;
  const int wr = (w >> 1) * 32, wc = (w & 1) * 64;
  f32x4 acc[2][4] = {};
  for (int kt = 0; kt < K; kt += 64) {
#pragma unroll
    for (int i = 0; i < 2; ++i) {
      int c = (i * 4 + w) * 64 + l;
      LOADLDS16(A + (size_t)(m0 + (c >> 3)) * K + kt + (c & 7) * 8,
                As + (size_t)(i * 4 + w) * 512);
    }
#pragma unroll
    for (int i = 0; i < 4; ++i) {
      int c = (i * 4 + w) * 64 + l;
      LOADLDS16(Bt + (size_t)(n0 + (c >> 3)) * K + kt + (c & 7) * 8,
                Bs + (size_t)(i * 4 + w) * 512);
    }
    __syncthreads();
#pragma unroll
    for (int kk = 0; kk < 2; ++kk) {
      f16x8 af[2], bf[4];
#pragma unroll
      for (int m = 0; m < 2; ++m)
        af[m] = *reinterpret_cast<const f16x8*>(As + (wr + m * 16 + lr) * 64 + kk * 32 + lq * 8);
#pragma unroll
      for (int n = 0; n < 4; ++n)
        bf[n] = *reinterpret_cast<const f16x8*>(Bs + (wc + n * 16 + lr) * 64 + kk * 32 + lq * 8);
#pragma unroll
      for (int m = 0; m < 2; ++m)
#pragma unroll
        for (int n = 0; n < 4; ++n)
          acc[m][n] = __builtin_amdgcn_mfma_f32_16x16x32_f16(af[m], bf[n], acc[m][n], 0, 0, 0);
    }
    __syncthreads();
  }
#pragma unroll
  for (int m = 0; m < 2; ++m)
#pragma unroll
    for (int n = 0; n < 4; ++n)
#pragma unroll
      for (int r = 0; r < 4; ++r) {
        int row = m0 + wr + m * 16 + lq * 4 + r;
        int col = n0 + wc + n * 16 + lr;
        out[(size_t)row * N + col] = acc[m][n][r];
      }
}

// ---------------------------------------------------------------------------
// V transpose per head: vb[bh][1024][64] -> vtb[bh][64][1024]
// ---------------------------------------------------------------------------
__global__ __launch_bounds__(256) void k_vtrans(const f16* __restrict__ vb,
                                                f16* __restrict__ vtb) {
  const int bh = blockIdx.y, s0 = blockIdx.x * 64;
  __shared__ f16 T[64][72];
  const int tid = threadIdx.x;
  const f16* src = vb + (size_t)bh * 1024 * 64;
#pragma unroll
  for (int i = 0; i < 2; ++i) {
    int c = i * 256 + tid;
    int row = c >> 3, co = (c & 7) * 8;
    f16x8 v = *reinterpret_cast<const f16x8*>(src + (size_t)(s0 + row) * 64 + co);
#pragma unroll
    for (int j = 0; j < 8; ++j) T[co + j][row] = v[j];
  }
  __syncthreads();
  f16* dst = vtb + (size_t)bh * 64 * 1024;
#pragma unroll
  for (int i = 0; i < 2; ++i) {
    int c = i * 256 + tid;
    int dh = c >> 3, so = (c & 7) * 8;
    f16x8 v;
#pragma unroll
    for (int j = 0; j < 8; ++j) v[j] = T[dh][so + j];
    *reinterpret_cast<f16x8*>(dst + (size_t)dh * 1024 + s0 + so) = v;
  }
}

// ---------------------------------------------------------------------------
// Fused flash attention (T5: scores = QK^T + bias, no 1/sqrt scale).
// v5: ALL staging via global_load_lds DMA (zero VGPR cost, can't spill, can't
// sink) -> 2-phase pipeline: issue tile t+1 at top of iter t, compute tile t,
// __syncthreads() (compiler emits vmcnt(0) drain before s_barrier).
// KVBLK=32, double-buffered. K/V use pre-swizzled GLOBAL source addresses
// (m173) + XOR-swizzled reads: 2-way max (free). Bias f32 staged linear
// (4-way on 8 reads = noise). Ps reg-written -> padded [16][40] (2-way).
// LDS = 8+8+16+5 = 37 KB -> 4 blocks/CU.
// XCD-chunked grid: each XCD owns 2 heads; b innermost -> bias L2-reuse.
// ---------------------------------------------------------------------------
__global__ __launch_bounds__(256) void k_attn(const f16* __restrict__ qb,
                                              const f16* __restrict__ kb,
                                              const f16* __restrict__ vtb,
                                              const float* __restrict__ bias,
                                              f16* __restrict__ ctx) {
  const int bid = blockIdx.x;
  const int ord = (bid & 7) * 128 + (bid >> 3);
  const int h = ord >> 6, qt = (ord >> 2) & 15, b = ord & 3;
  const int bh = b * 16 + h;
  const int q0 = qt * 64;
  const int tid = threadIdx.x, w = tid >> 6, l = tid & 63;
  const int lr = l & 15, lq = l >> 4;

  __shared__ f16 Kb[2][2048];   // [kv=32][dh=64], granule-swizzled: gg = g ^ (row&7)
  __shared__ f16 Vb[2][2048];   // [dh=64][kv=32], granule-swizzled: gg = g ^ ((row>>1)&3)
  __shared__ float Bbf[2][2048];// [q=64][kv=32], linear
  __shared__ f16 Ps[4][640];    // per-wave [16][40] padded

  // Q fragment: A-frag rows = lr, k-chunks dh = lq*8 (+32)
  const f16* qp = qb + ((size_t)bh * 1024 + q0 + w * 16 + lr) * 64 + lq * 8;
  f16x8 qf0 = *reinterpret_cast<const f16x8*>(qp);
  f16x8 qf1 = *reinterpret_cast<const f16x8*>(qp + 32);

  f32x4 O[4] = {};
  float mrun[4], lrun[4];
#pragma unroll
  for (int r = 0; r < 4; ++r) { mrun[r] = -3.0e38f; lrun[r] = 0.f; }

  const f16* kbase = kb + (size_t)bh * 1024 * 64;
  const f16* vbase = vtb + (size_t)bh * 64 * 1024;
  const float* bbase = bias + ((size_t)h * 1024 + q0) * 1024;

  // per-lane staging geometry (wave-uniform LDS bases; per-lane global src)
  const int krow = w * 8 + (l >> 3);          // K tile row (kv)
  const int kg = (l & 7) ^ (l >> 3);          // pre-swizzled dh granule
  const int vrow = w * 16 + (l >> 2);         // V tile row (dh)
  const int vg = (l & 3) ^ ((l >> 3) & 3);    // pre-swizzled kv granule
  const int brow = w * 16 + (l >> 3);         // bias rows (2 chunks of 8)
  const int bg = l & 7;

  auto stage = [&](int t, int nxt) {
    LOADLDS16(kbase + (size_t)(t * 32 + krow) * 64 + kg * 8, &Kb[nxt][w * 512]);
    LOADLDS16(vbase + (size_t)vrow * 1024 + t * 32 + vg * 8, &Vb[nxt][w * 512]);
    LOADLDS16(bbase + (size_t)brow * 1024 + t * 32 + bg * 4, &Bbf[nxt][w * 512]);
    LOADLDS16(bbase + (size_t)(brow + 8) * 1024 + t * 32 + bg * 4,
              &Bbf[nxt][w * 512 + 256]);
  };

  // ---- prologue: stage tile 0 (syncthreads drains vmcnt) ----
  stage(0, 0);
  __syncthreads();

#pragma unroll 1
  for (int t = 0; t < 32; ++t) {
    const int cur = t & 1;
    // ---- issue next tile's DMA (in-flight across the whole body) ----
    if (t < 31) stage(t + 1, cur ^ 1);
    __builtin_amdgcn_sched_barrier(0);

    // ---- S = Q K^T  (rows q_loc = lq*4+r, cols k = c*16+lr) ----
    f32x4 S[2] = {};
    __builtin_amdgcn_s_setprio(1);
#pragma unroll
    for (int c = 0; c < 2; ++c) {
      int row = c * 16 + lr;
      const f16* kbp = &Kb[cur][row * 64];
      f16x8 kf0 = *reinterpret_cast<const f16x8*>(kbp + ((lq ^ (lr & 7)) * 8));
      f16x8 kf1 = *reinterpret_cast<const f16x8*>(kbp + (((4 + lq) ^ (lr & 7)) * 8));
      S[c] = __builtin_amdgcn_mfma_f32_16x16x32_f16(qf0, kf0, S[c], 0, 0, 0);
      S[c] = __builtin_amdgcn_mfma_f32_16x16x32_f16(qf1, kf1, S[c], 0, 0, 0);
    }
    __builtin_amdgcn_s_setprio(0);

    // ---- + position bias (from LDS, landed last iteration) ----
#pragma unroll
    for (int c = 0; c < 2; ++c)
#pragma unroll
      for (int r = 0; r < 4; ++r)
        S[c][r] += Bbf[cur][(w * 16 + lq * 4 + r) * 32 + c * 16 + lr];

    // ---- online softmax over k (16 lanes of lr x 2 c-blocks) ----
    float tmax[4];
#pragma unroll
    for (int r = 0; r < 4; ++r) tmax[r] = fmaxf(S[0][r], S[1][r]);
#pragma unroll
    for (int msk = 1; msk <= 8; msk <<= 1)
#pragma unroll
      for (int r = 0; r < 4; ++r)
        tmax[r] = fmaxf(tmax[r], __shfl_xor(tmax[r], msk, 64));
    float scale[4], rsum[4];
#pragma unroll
    for (int r = 0; r < 4; ++r) {
      float mnew = fmaxf(mrun[r], tmax[r]);
      scale[r] = __expf(mrun[r] - mnew);
      mrun[r] = mnew;
      rsum[r] = 0.f;
    }
#pragma unroll
    for (int c = 0; c < 2; ++c)
#pragma unroll
      for (int r = 0; r < 4; ++r) {
        float p = __expf(S[c][r] - mrun[r]);
        S[c][r] = p;
        rsum[r] += p;
      }
#pragma unroll
    for (int msk = 1; msk <= 8; msk <<= 1)
#pragma unroll
      for (int r = 0; r < 4; ++r) rsum[r] += __shfl_xor(rsum[r], msk, 64);
#pragma unroll
    for (int r = 0; r < 4; ++r) lrun[r] = lrun[r] * scale[r] + rsum[r];

    // ---- rescale O, spill P (wave-private padded; lgkmcnt orders) ----
#pragma unroll
    for (int c = 0; c < 2; ++c)
#pragma unroll
      for (int r = 0; r < 4; ++r) {
        Ps[w][(lq * 4 + r) * 40 + c * 16 + lr] = (f16)S[c][r];
      }
#pragma unroll
    for (int c = 0; c < 4; ++c)
#pragma unroll
      for (int r = 0; r < 4; ++r) O[c][r] *= scale[r];

    // ---- O += P @ V ----
    {
      f16x8 pa = *reinterpret_cast<const f16x8*>(&Ps[w][lr * 40 + lq * 8]);
      __builtin_amdgcn_s_setprio(1);
#pragma unroll
      for (int c = 0; c < 4; ++c) {
        int row = c * 16 + lr;
        f16x8 vf = *reinterpret_cast<const f16x8*>(
            &Vb[cur][row * 32 + ((lq ^ ((lr >> 1) & 3)) * 8)]);
        O[c] = __builtin_amdgcn_mfma_f32_16x16x32_f16(pa, vf, O[c], 0, 0, 0);
      }
      __builtin_amdgcn_s_setprio(0);
    }

    __syncthreads();
  }

  // ---- epilogue: ctx[b][q][h*64+dh] f16 ----
#pragma unroll
  for (int c = 0; c < 4; ++c)
#pragma unroll
    for (int r = 0; r < 4; ++r) {
      float o = O[c][r] / lrun[r];
      int row = q0 + w * 16 + lq * 4 + r;
      ctx[((size_t)b * 1024 + row) * 1024 + h * 64 + c * 16 + lr] = (f16)o;
    }
}

// ---------------------------------------------------------------------------
extern "C" void kernel_launch(void* const* d_in, const int* in_sizes, int n_in,
                              void* d_out, int out_size, void* d_ws,
                              size_t ws_size, hipStream_t stream) {
  const float* input_ids = (const float*)d_in[0];
  const float* enc = (const float*)d_in[1];
  const float* bias = (const float*)d_in[2];
  const float* Wq = (const float*)d_in[3];
  const float* Wk = (const float*)d_in[4];
  const float* Wv = (const float*)d_in[5];
  const float* Wo = (const float*)d_in[6];

  char* ws = (char*)d_ws;
  const size_t MB = 1024 * 1024;
  f16* Xq  = (f16*)(ws + 0 * MB);   // 8 MB; dead after QKV-proj -> reused as ctx
  f16* Xkv = (f16*)(ws + 8 * MB);   // 8 MB; dead after QKV-proj -> reused as vtb
  f16* Wqt = (f16*)(ws + 16 * MB);  // 2 MB each; Wqt|Wkt|Wvt contiguous = [3072][1024]
  f16* Wkt = (f16*)(ws + 18 * MB);
  f16* Wvt = (f16*)(ws + 20 * MB);
  f16* Wot = (f16*)(ws + 22 * MB);
  f16* qbuf = (f16*)(ws + 24 * MB); // 8 MB [bh][s][dh]; kbuf/vbuf planes follow
  f16* kbuf = (f16*)(ws + 32 * MB);
  f16* vbuf = (f16*)(ws + 40 * MB);
  f16* vtb = Xkv;   // [bh][dh][sk]
  f16* ctxb = Xq;   // [4096][1024]

  k_cast<<<4096, 256, 0, stream>>>(input_ids, Xq, 1048576);
  k_cast<<<4096, 256, 0, stream>>>(enc, Xkv, 1048576);
  k_castw_t<<<dim3(16, 16, 4), 256, 0, stream>>>(Wq, Wk, Wv, Wo, Wqt, Wkt, Wvt, Wot);

  // fused Q+K+V projection: N=3072 over [Wqt|Wkt|Wvt], per-block A select
  k_gemm_qkv<<<dim3(24, 32), 256, 0, stream>>>(Xq, Xkv, Wqt, qbuf);

  k_vtrans<<<dim3(16, 64), 256, 0, stream>>>(vbuf, vtb);

  k_attn<<<1024, 256, 0, stream>>>(qbuf, kbuf, vtb, bias, ctxb);

  k_gemm_o<<<dim3(8, 64), 256, 0, stream>>>(ctxb, Wot, (float*)d_out, 4096, 1024, 1024);
}

// Round 6
// 149.985 us; speedup vs baseline: 7.4321x; 1.2602x over previous
//
#include <hip/hip_runtime.h>

typedef _Float16 f16;
typedef _Float16 f16x4 __attribute__((ext_vector_type(4)));
typedef _Float16 f16x8 __attribute__((ext_vector_type(8)));
typedef float f32x4 __attribute__((ext_vector_type(4)));

// async global->LDS, 16B per lane; LDS dest = wave-uniform base + lane*16
#define LOADLDS16(gp, lp)                                                     \
  __builtin_amdgcn_global_load_lds(                                           \
      (const __attribute__((address_space(1))) void*)(gp),                    \
      (__attribute__((address_space(3))) void*)(lp), 16, 0, 0)

// ---------------------------------------------------------------------------
// Elementwise cast f32 -> f16 (vectorized)
// ---------------------------------------------------------------------------
__global__ __launch_bounds__(256) void k_cast(const float* __restrict__ x,
                                              f16* __restrict__ y, int n4) {
  int i = blockIdx.x * 256 + threadIdx.x;
  if (i >= n4) return;
  float4 v = reinterpret_cast<const float4*>(x)[i];
  f16x4 o;
  o[0] = (f16)v.x; o[1] = (f16)v.y; o[2] = (f16)v.z; o[3] = (f16)v.w;
  reinterpret_cast<f16x4*>(y)[i] = o;
}

// ---------------------------------------------------------------------------
// Cast + transpose weights: W[1024][1024] f32 -> Wt[N][K] f16  (Wt[n][k]=W[k][n])
// ---------------------------------------------------------------------------
__global__ __launch_bounds__(256) void k_castw_t(
    const float* __restrict__ w0, const float* __restrict__ w1,
    const float* __restrict__ w2, const float* __restrict__ w3,
    f16* __restrict__ o0, f16* __restrict__ o1, f16* __restrict__ o2,
    f16* __restrict__ o3) {
  const float* W;
  f16* O;
  switch (blockIdx.z) {
    case 0: W = w0; O = o0; break;
    case 1: W = w1; O = o1; break;
    case 2: W = w2; O = o2; break;
    default: W = w3; O = o3; break;
  }
  __shared__ f16 T[64][72];
  const int tid = threadIdx.x;
  const int r0 = blockIdx.y * 64, c0 = blockIdx.x * 64;
#pragma unroll
  for (int i = 0; i < 4; ++i) {
    int c = i * 256 + tid;
    int row = c >> 4, col = (c & 15) * 4;
    float4 v = *reinterpret_cast<const float4*>(W + (size_t)(r0 + row) * 1024 + c0 + col);
    T[col + 0][row] = (f16)v.x;
    T[col + 1][row] = (f16)v.y;
    T[col + 2][row] = (f16)v.z;
    T[col + 3][row] = (f16)v.w;
  }
  __syncthreads();
#pragma unroll
  for (int i = 0; i < 2; ++i) {
    int c = i * 256 + tid;
    int cc = c >> 3, ro = (c & 7) * 8;
    f16x8 v;
#pragma unroll
    for (int j = 0; j < 8; ++j) v[j] = T[cc][ro + j];
    *reinterpret_cast<f16x8*>(O + (size_t)(c0 + cc) * 1024 + r0 + ro) = v;
  }
}

// ---------------------------------------------------------------------------
// Fused QKV projection: C[4096, 3072] where cols 0-1023 = Xq@Wqt, 1024-2047 =
// Xkv@Wkt, 2048-3071 = Xkv@Wvt. m97 structure: BM=BN=128, BK=64, 4 waves,
// 4x4 acc/wave, global_load_lds x16B. Bt = [Wqt|Wkt|Wvt] rows (contiguous ws).
// ---------------------------------------------------------------------------
__global__ __launch_bounds__(256) void k_gemm_qkv(const f16* __restrict__ Xq,
                                                  const f16* __restrict__ Xkv,
                                                  const f16* __restrict__ Bt,
                                                  f16* __restrict__ outp) {
  __shared__ f16 As[128 * 64];  // 16 KB
  __shared__ f16 Bs[128 * 64];  // 16 KB
  const int tid = threadIdx.x;
  const int w = tid >> 6, l = tid & 63;
  const int lr = l & 15, lq = l >> 4;
  const int m0 = blockIdx.y * 128, n0 = blockIdx.x * 128;
  const f16* A = (n0 < 1024) ? Xq : Xkv;
  const int wr = (w >> 1) * 64, wc = (w & 1) * 64;
  const int K = 1024;
  f32x4 acc[4][4] = {};
  for (int kt = 0; kt < K; kt += 64) {
#pragma unroll
    for (int i = 0; i < 4; ++i) {
      int c = (i * 4 + w) * 64 + l;
      LOADLDS16(A + (size_t)(m0 + (c >> 3)) * K + kt + (c & 7) * 8,
                As + (size_t)(i * 4 + w) * 512);
      LOADLDS16(Bt + (size_t)(n0 + (c >> 3)) * K + kt + (c & 7) * 8,
                Bs + (size_t)(i * 4 + w) * 512);
    }
    __syncthreads();
#pragma unroll
    for (int kk = 0; kk < 2; ++kk) {
      f16x8 af[4], bf[4];
#pragma unroll
      for (int m = 0; m < 4; ++m)
        af[m] = *reinterpret_cast<const f16x8*>(As + (wr + m * 16 + lr) * 64 + kk * 32 + lq * 8);
#pragma unroll
      for (int n = 0; n < 4; ++n)
        bf[n] = *reinterpret_cast<const f16x8*>(Bs + (wc + n * 16 + lr) * 64 + kk * 32 + lq * 8);
#pragma unroll
      for (int m = 0; m < 4; ++m)
#pragma unroll
        for (int n = 0; n < 4; ++n)
          acc[m][n] = __builtin_amdgcn_mfma_f32_16x16x32_f16(af[m], bf[n], acc[m][n], 0, 0, 0);
    }
    __syncthreads();
  }
#pragma unroll
  for (int m = 0; m < 4; ++m)
#pragma unroll
    for (int n = 0; n < 4; ++n)
#pragma unroll
      for (int r = 0; r < 4; ++r) {
        int row = m0 + wr + m * 16 + lq * 4 + r;
        int col = n0 + wc + n * 16 + lr;
        int b = row >> 10, s = row & 1023;
        int plane = col >> 10, cc = col & 1023;
        int h = cc >> 6, dh = cc & 63;
        outp[(size_t)plane * 4194304 +
             (((size_t)(b * 16 + h)) * 1024 + s) * 64 + dh] = (f16)acc[m][n][r];
      }
}

// ---------------------------------------------------------------------------
// Output GEMM: C[M,N] f32 = A[M,K] @ Bt[N,K]^T. BM=64, BN=128 (512 blocks).
// ---------------------------------------------------------------------------
__global__ __launch_bounds__(256) void k_gemm_o(const f16* __restrict__ A,
                                                const f16* __restrict__ Bt,
                                                float* __restrict__ out, int M,
                                                int N, int K) {
  __shared__ f16 As[64 * 64];
  __shared__ f16 Bs[128 * 64];
  const int tid = threadIdx.x;
  const int w = tid >> 6, l = tid & 63;
  const int lr = l & 15, lq = l >> 4;
  const int m0 = blockIdx.y * 64, n0 = blockIdx.x * 128;
  const int wr = (w >> 1) * 32, wc = (w & 1) * 64;
  f32x4 acc[2][4] = {};
  for (int kt = 0; kt < K; kt += 64) {
#pragma unroll
    for (int i = 0; i < 2; ++i) {
      int c = (i * 4 + w) * 64 + l;
      LOADLDS16(A + (size_t)(m0 + (c >> 3)) * K + kt + (c & 7) * 8,
                As + (size_t)(i * 4 + w) * 512);
    }
#pragma unroll
    for (int i = 0; i < 4; ++i) {
      int c = (i * 4 + w) * 64 + l;
      LOADLDS16(Bt + (size_t)(n0 + (c >> 3)) * K + kt + (c & 7) * 8,
                Bs + (size_t)(i * 4 + w) * 512);
    }
    __syncthreads();
#pragma unroll
    for (int kk = 0; kk < 2; ++kk) {
      f16x8 af[2], bf[4];
#pragma unroll
      for (int m = 0; m < 2; ++m)
        af[m] = *reinterpret_cast<const f16x8*>(As + (wr + m * 16 + lr) * 64 + kk * 32 + lq * 8);
#pragma unroll
      for (int n = 0; n < 4; ++n)
        bf[n] = *reinterpret_cast<const f16x8*>(Bs + (wc + n * 16 + lr) * 64 + kk * 32 + lq * 8);
#pragma unroll
      for (int m = 0; m < 2; ++m)
#pragma unroll
        for (int n = 0; n < 4; ++n)
          acc[m][n] = __builtin_amdgcn_mfma_f32_16x16x32_f16(af[m], bf[n], acc[m][n], 0, 0, 0);
    }
    __syncthreads();
  }
#pragma unroll
  for (int m = 0; m < 2; ++m)
#pragma unroll
    for (int n = 0; n < 4; ++n)
#pragma unroll
      for (int r = 0; r < 4; ++r) {
        int row = m0 + wr + m * 16 + lq * 4 + r;
        int col = n0 + wc + n * 16 + lr;
        out[(size_t)row * N + col] = acc[m][n][r];
      }
}

// ---------------------------------------------------------------------------
// V transpose per head: vb[bh][1024][64] -> vtb[bh][64][1024]
// ---------------------------------------------------------------------------
__global__ __launch_bounds__(256) void k_vtrans(const f16* __restrict__ vb,
                                                f16* __restrict__ vtb) {
  const int bh = blockIdx.y, s0 = blockIdx.x * 64;
  __shared__ f16 T[64][72];
  const int tid = threadIdx.x;
  const f16* src = vb + (size_t)bh * 1024 * 64;
#pragma unroll
  for (int i = 0; i < 2; ++i) {
    int c = i * 256 + tid;
    int row = c >> 3, co = (c & 7) * 8;
    f16x8 v = *reinterpret_cast<const f16x8*>(src + (size_t)(s0 + row) * 64 + co);
#pragma unroll
    for (int j = 0; j < 8; ++j) T[co + j][row] = v[j];
  }
  __syncthreads();
  f16* dst = vtb + (size_t)bh * 64 * 1024;
#pragma unroll
  for (int i = 0; i < 2; ++i) {
    int c = i * 256 + tid;
    int dh = c >> 3, so = (c & 7) * 8;
    f16x8 v;
#pragma unroll
    for (int j = 0; j < 8; ++j) v[j] = T[dh][so + j];
    *reinterpret_cast<f16x8*>(dst + (size_t)dh * 1024 + s0 + so) = v;
  }
}

// ---------------------------------------------------------------------------
// Fused flash attention (T5: scores = QK^T + bias, no 1/sqrt scale).
// v6: DMA 2-phase staging (round-5, kept) + DEFER-MAX (T13): mrun is
// row-uniform; per tile only a per-lane bound check + wave __all. Common
// path has ZERO cross-lane ops (no shuffles, no rescale): bias-add, exp,
// per-lane partial rsum (reduced ONCE after the loop), P write, PV.
// Rare path (tile 0 + max-growth events): full shuffle reduce + rescale.
// P = exp(S - mrun) <= e^8 = 2981 -> f16-safe.
// Bias LDS granule-XOR swizzled (stage src granule g^(row&7)) -> 2-way reads.
// ---------------------------------------------------------------------------
__global__ __launch_bounds__(256) void k_attn(const f16* __restrict__ qb,
                                              const f16* __restrict__ kb,
                                              const f16* __restrict__ vtb,
                                              const float* __restrict__ bias,
                                              f16* __restrict__ ctx) {
  const int bid = blockIdx.x;
  const int ord = (bid & 7) * 128 + (bid >> 3);
  const int h = ord >> 6, qt = (ord >> 2) & 15, b = ord & 3;
  const int bh = b * 16 + h;
  const int q0 = qt * 64;
  const int tid = threadIdx.x, w = tid >> 6, l = tid & 63;
  const int lr = l & 15, lq = l >> 4;

  __shared__ f16 Kb[2][2048];   // [kv=32][dh=64], granule-swizzled
  __shared__ f16 Vb[2][2048];   // [dh=64][kv=32], granule-swizzled
  __shared__ float Bbf[2][2048];// [q=64][kv=32], granule-swizzled: g^(row&7)
  __shared__ f16 Ps[4][640];    // per-wave [16][40] padded

  const f16* qp = qb + ((size_t)bh * 1024 + q0 + w * 16 + lr) * 64 + lq * 8;
  f16x8 qf0 = *reinterpret_cast<const f16x8*>(qp);
  f16x8 qf1 = *reinterpret_cast<const f16x8*>(qp + 32);

  f32x4 O[4] = {};
  float mrun[4], rsum[4];
#pragma unroll
  for (int r = 0; r < 4; ++r) { mrun[r] = -3.0e38f; rsum[r] = 0.f; }

  const f16* kbase = kb + (size_t)bh * 1024 * 64;
  const f16* vbase = vtb + (size_t)bh * 64 * 1024;
  const float* bbase = bias + ((size_t)h * 1024 + q0) * 1024;

  // per-lane staging geometry (wave-uniform LDS bases; per-lane global src)
  const int krow = w * 8 + (l >> 3);          // K tile row (kv)
  const int kg = (l & 7) ^ (l >> 3);          // pre-swizzled dh granule
  const int vrow = w * 16 + (l >> 2);         // V tile row (dh)
  const int vg = (l & 3) ^ ((l >> 3) & 3);    // pre-swizzled kv granule
  const int brow = w * 16 + (l >> 3);         // bias rows (2 chunks of 8)
  const int bgs = (l & 7) ^ ((l >> 3) & 7);   // pre-swizzled bias granule

  auto stage = [&](int t, int nxt) {
    LOADLDS16(kbase + (size_t)(t * 32 + krow) * 64 + kg * 8, &Kb[nxt][w * 512]);
    LOADLDS16(vbase + (size_t)vrow * 1024 + t * 32 + vg * 8, &Vb[nxt][w * 512]);
    LOADLDS16(bbase + (size_t)brow * 1024 + t * 32 + bgs * 4, &Bbf[nxt][w * 512]);
    LOADLDS16(bbase + (size_t)(brow + 8) * 1024 + t * 32 + bgs * 4,
              &Bbf[nxt][w * 512 + 256]);
  };

  // ---- prologue: stage tile 0 (syncthreads drains vmcnt) ----
  stage(0, 0);
  __syncthreads();

#pragma unroll 1
  for (int t = 0; t < 32; ++t) {
    const int cur = t & 1;
    // ---- issue next tile's DMA (in-flight across the whole body) ----
    if (t < 31) stage(t + 1, cur ^ 1);
    __builtin_amdgcn_sched_barrier(0);

    // ---- S = Q K^T  (rows q_loc = lq*4+r, cols k = c*16+lr) ----
    f32x4 S[2] = {};
    __builtin_amdgcn_s_setprio(1);
#pragma unroll
    for (int c = 0; c < 2; ++c) {
      int row = c * 16 + lr;
      const f16* kbp = &Kb[cur][row * 64];
      f16x8 kf0 = *reinterpret_cast<const f16x8*>(kbp + ((lq ^ (lr & 7)) * 8));
      f16x8 kf1 = *reinterpret_cast<const f16x8*>(kbp + (((4 + lq) ^ (lr & 7)) * 8));
      S[c] = __builtin_amdgcn_mfma_f32_16x16x32_f16(qf0, kf0, S[c], 0, 0, 0);
      S[c] = __builtin_amdgcn_mfma_f32_16x16x32_f16(qf1, kf1, S[c], 0, 0, 0);
    }
    __builtin_amdgcn_s_setprio(0);

    // ---- + position bias (granule-swizzled LDS) ----
#pragma unroll
    for (int c = 0; c < 2; ++c)
#pragma unroll
      for (int r = 0; r < 4; ++r) {
        int row = w * 16 + lq * 4 + r;
        int G = c * 4 + (lr >> 2);
        S[c][r] += Bbf[cur][row * 32 + ((G ^ (row & 7)) << 2) + (lr & 3)];
      }

    // ---- defer-max: per-lane bound check, rare full reduce+rescale ----
    float tmax[4];
#pragma unroll
    for (int r = 0; r < 4; ++r) tmax[r] = fmaxf(S[0][r], S[1][r]);
    bool ok = true;
#pragma unroll
    for (int r = 0; r < 4; ++r) ok = ok && (tmax[r] <= mrun[r] + 8.0f);
    if (!__all(ok)) {
#pragma unroll
      for (int msk = 1; msk <= 8; msk <<= 1)
#pragma unroll
        for (int r = 0; r < 4; ++r)
          tmax[r] = fmaxf(tmax[r], __shfl_xor(tmax[r], msk, 64));
#pragma unroll
      for (int r = 0; r < 4; ++r) {
        float mnew = fmaxf(mrun[r], tmax[r]);
        float sc = __expf(mrun[r] - mnew);
        mrun[r] = mnew;
        rsum[r] *= sc;
#pragma unroll
        for (int c = 0; c < 4; ++c) O[c][r] *= sc;
      }
    }

    // ---- P = exp(S - mrun); per-lane partial rsum; spill P to Ps ----
#pragma unroll
    for (int c = 0; c < 2; ++c)
#pragma unroll
      for (int r = 0; r < 4; ++r) {
        float p = __expf(S[c][r] - mrun[r]);
        rsum[r] += p;
        Ps[w][(lq * 4 + r) * 40 + c * 16 + lr] = (f16)p;
      }

    // ---- O += P @ V (lgkmcnt orders the wave-private round-trip) ----
    {
      f16x8 pa = *reinterpret_cast<const f16x8*>(&Ps[w][lr * 40 + lq * 8]);
      __builtin_amdgcn_s_setprio(1);
#pragma unroll
      for (int c = 0; c < 4; ++c) {
        int row = c * 16 + lr;
        f16x8 vf = *reinterpret_cast<const f16x8*>(
            &Vb[cur][row * 32 + ((lq ^ ((lr >> 1) & 3)) * 8)]);
        O[c] = __builtin_amdgcn_mfma_f32_16x16x32_f16(pa, vf, O[c], 0, 0, 0);
      }
      __builtin_amdgcn_s_setprio(0);
    }

    __syncthreads();
  }

  // ---- deferred sum reduction (once) ----
#pragma unroll
  for (int msk = 1; msk <= 8; msk <<= 1)
#pragma unroll
    for (int r = 0; r < 4; ++r) rsum[r] += __shfl_xor(rsum[r], msk, 64);

  // ---- epilogue: ctx[b][q][h*64+dh] f16 ----
#pragma unroll
  for (int c = 0; c < 4; ++c)
#pragma unroll
    for (int r = 0; r < 4; ++r) {
      float o = O[c][r] / rsum[r];
      int row = q0 + w * 16 + lq * 4 + r;
      ctx[((size_t)b * 1024 + row) * 1024 + h * 64 + c * 16 + lr] = (f16)o;
    }
}

// ---------------------------------------------------------------------------
extern "C" void kernel_launch(void* const* d_in, const int* in_sizes, int n_in,
                              void* d_out, int out_size, void* d_ws,
                              size_t ws_size, hipStream_t stream) {
  const float* input_ids = (const float*)d_in[0];
  const float* enc = (const float*)d_in[1];
  const float* bias = (const float*)d_in[2];
  const float* Wq = (const float*)d_in[3];
  const float* Wk = (const float*)d_in[4];
  const float* Wv = (const float*)d_in[5];
  const float* Wo = (const float*)d_in[6];

  char* ws = (char*)d_ws;
  const size_t MB = 1024 * 1024;
  f16* Xq  = (f16*)(ws + 0 * MB);   // 8 MB; dead after QKV-proj -> reused as ctx
  f16* Xkv = (f16*)(ws + 8 * MB);   // 8 MB; dead after QKV-proj -> reused as vtb
  f16* Wqt = (f16*)(ws + 16 * MB);  // 2 MB each; Wqt|Wkt|Wvt contiguous = [3072][1024]
  f16* Wkt = (f16*)(ws + 18 * MB);
  f16* Wvt = (f16*)(ws + 20 * MB);
  f16* Wot = (f16*)(ws + 22 * MB);
  f16* qbuf = (f16*)(ws + 24 * MB); // 8 MB [bh][s][dh]; kbuf/vbuf planes follow
  f16* kbuf = (f16*)(ws + 32 * MB);
  f16* vbuf = (f16*)(ws + 40 * MB);
  f16* vtb = Xkv;   // [bh][dh][sk]
  f16* ctxb = Xq;   // [4096][1024]

  k_cast<<<4096, 256, 0, stream>>>(input_ids, Xq, 1048576);
  k_cast<<<4096, 256, 0, stream>>>(enc, Xkv, 1048576);
  k_castw_t<<<dim3(16, 16, 4), 256, 0, stream>>>(Wq, Wk, Wv, Wo, Wqt, Wkt, Wvt, Wot);

  // fused Q+K+V projection: N=3072 over [Wqt|Wkt|Wvt], per-block A select
  k_gemm_qkv<<<dim3(24, 32), 256, 0, stream>>>(Xq, Xkv, Wqt, qbuf);

  k_vtrans<<<dim3(16, 64), 256, 0, stream>>>(vbuf, vtb);

  k_attn<<<1024, 256, 0, stream>>>(qbuf, kbuf, vtb, bias, ctxb);

  k_gemm_o<<<dim3(8, 64), 256, 0, stream>>>(ctxb, Wot, (float*)d_out, 4096, 1024, 1024);
}

// Round 7
// 140.058 us; speedup vs baseline: 7.9589x; 1.0709x over previous
//
#include <hip/hip_runtime.h>

typedef _Float16 f16;
typedef _Float16 f16x4 __attribute__((ext_vector_type(4)));
typedef _Float16 f16x8 __attribute__((ext_vector_type(8)));
typedef float f32x4 __attribute__((ext_vector_type(4)));

// async global->LDS, 16B per lane; LDS dest = wave-uniform base + lane*16
#define LOADLDS16(gp, lp)                                                     \
  __builtin_amdgcn_global_load_lds(                                           \
      (const __attribute__((address_space(1))) void*)(gp),                    \
      (__attribute__((address_space(3))) void*)(lp), 16, 0, 0)

// ---------------------------------------------------------------------------
// Elementwise cast f32 -> f16 (both activations in one launch)
// ---------------------------------------------------------------------------
__global__ __launch_bounds__(256) void k_cast2(const float* __restrict__ a,
                                               const float* __restrict__ b,
                                               f16* __restrict__ ya,
                                               f16* __restrict__ yb) {
  int i = blockIdx.x * 256 + threadIdx.x;
  const float* x;
  f16* y;
  if (i < 1048576) {
    x = a; y = ya;
  } else {
    x = b; y = yb; i -= 1048576;
  }
  float4 v = reinterpret_cast<const float4*>(x)[i];
  f16x4 o;
  o[0] = (f16)v.x; o[1] = (f16)v.y; o[2] = (f16)v.z; o[3] = (f16)v.w;
  reinterpret_cast<f16x4*>(y)[i] = o;
}

// ---------------------------------------------------------------------------
// Cast + transpose weights: W[1024][1024] f32 -> Wt[N][K] f16  (Wt[n][k]=W[k][n])
// ---------------------------------------------------------------------------
__global__ __launch_bounds__(256) void k_castw_t(
    const float* __restrict__ w0, const float* __restrict__ w1,
    const float* __restrict__ w2, const float* __restrict__ w3,
    f16* __restrict__ o0, f16* __restrict__ o1, f16* __restrict__ o2,
    f16* __restrict__ o3) {
  const float* W;
  f16* O;
  switch (blockIdx.z) {
    case 0: W = w0; O = o0; break;
    case 1: W = w1; O = o1; break;
    case 2: W = w2; O = o2; break;
    default: W = w3; O = o3; break;
  }
  __shared__ f16 T[64][72];
  const int tid = threadIdx.x;
  const int r0 = blockIdx.y * 64, c0 = blockIdx.x * 64;
#pragma unroll
  for (int i = 0; i < 4; ++i) {
    int c = i * 256 + tid;
    int row = c >> 4, col = (c & 15) * 4;
    float4 v = *reinterpret_cast<const float4*>(W + (size_t)(r0 + row) * 1024 + c0 + col);
    T[col + 0][row] = (f16)v.x;
    T[col + 1][row] = (f16)v.y;
    T[col + 2][row] = (f16)v.z;
    T[col + 3][row] = (f16)v.w;
  }
  __syncthreads();
#pragma unroll
  for (int i = 0; i < 2; ++i) {
    int c = i * 256 + tid;
    int cc = c >> 3, ro = (c & 7) * 8;
    f16x8 v;
#pragma unroll
    for (int j = 0; j < 8; ++j) v[j] = T[cc][ro + j];
    *reinterpret_cast<f16x8*>(O + (size_t)(c0 + cc) * 1024 + r0 + ro) = v;
  }
}

// ---------------------------------------------------------------------------
// Fused QKV projection: C[4096, 3072], cols 0-1023 = Xq@Wqt, 1024-2047 =
// Xkv@Wkt, 2048-3071 = Xkv@Wvt. m97 structure: BM=BN=128, BK=64, 4 waves.
// ---------------------------------------------------------------------------
__global__ __launch_bounds__(256) void k_gemm_qkv(const f16* __restrict__ Xq,
                                                  const f16* __restrict__ Xkv,
                                                  const f16* __restrict__ Bt,
                                                  f16* __restrict__ outp) {
  __shared__ f16 As[128 * 64];  // 16 KB
  __shared__ f16 Bs[128 * 64];  // 16 KB
  const int tid = threadIdx.x;
  const int w = tid >> 6, l = tid & 63;
  const int lr = l & 15, lq = l >> 4;
  const int m0 = blockIdx.y * 128, n0 = blockIdx.x * 128;
  const f16* A = (n0 < 1024) ? Xq : Xkv;
  const int wr = (w >> 1) * 64, wc = (w & 1) * 64;
  const int K = 1024;
  f32x4 acc[4][4] = {};
  for (int kt = 0; kt < K; kt += 64) {
#pragma unroll
    for (int i = 0; i < 4; ++i) {
      int c = (i * 4 + w) * 64 + l;
      LOADLDS16(A + (size_t)(m0 + (c >> 3)) * K + kt + (c & 7) * 8,
                As + (size_t)(i * 4 + w) * 512);
      LOADLDS16(Bt + (size_t)(n0 + (c >> 3)) * K + kt + (c & 7) * 8,
                Bs + (size_t)(i * 4 + w) * 512);
    }
    __syncthreads();
#pragma unroll
    for (int kk = 0; kk < 2; ++kk) {
      f16x8 af[4], bf[4];
#pragma unroll
      for (int m = 0; m < 4; ++m)
        af[m] = *reinterpret_cast<const f16x8*>(As + (wr + m * 16 + lr) * 64 + kk * 32 + lq * 8);
#pragma unroll
      for (int n = 0; n < 4; ++n)
        bf[n] = *reinterpret_cast<const f16x8*>(Bs + (wc + n * 16 + lr) * 64 + kk * 32 + lq * 8);
#pragma unroll
      for (int m = 0; m < 4; ++m)
#pragma unroll
        for (int n = 0; n < 4; ++n)
          acc[m][n] = __builtin_amdgcn_mfma_f32_16x16x32_f16(af[m], bf[n], acc[m][n], 0, 0, 0);
    }
    __syncthreads();
  }
#pragma unroll
  for (int m = 0; m < 4; ++m)
#pragma unroll
    for (int n = 0; n < 4; ++n)
#pragma unroll
      for (int r = 0; r < 4; ++r) {
        int row = m0 + wr + m * 16 + lq * 4 + r;
        int col = n0 + wc + n * 16 + lr;
        int b = row >> 10, s = row & 1023;
        int plane = col >> 10, cc = col & 1023;
        int h = cc >> 6, dh = cc & 63;
        outp[(size_t)plane * 4194304 +
             (((size_t)(b * 16 + h)) * 1024 + s) * 64 + dh] = (f16)acc[m][n][r];
      }
}

// ---------------------------------------------------------------------------
// Output GEMM: C[M,N] f32 = A[M,K] @ Bt[N,K]^T. BM=64, BN=128 (512 blocks).
// ---------------------------------------------------------------------------
__global__ __launch_bounds__(256) void k_gemm_o(const f16* __restrict__ A,
                                                const f16* __restrict__ Bt,
                                                float* __restrict__ out, int M,
                                                int N, int K) {
  __shared__ f16 As[64 * 64];
  __shared__ f16 Bs[128 * 64];
  const int tid = threadIdx.x;
  const int w = tid >> 6, l = tid & 63;
  const int lr = l & 15, lq = l >> 4;
  const int m0 = blockIdx.y * 64, n0 = blockIdx.x * 128;
  const int wr = (w >> 1) * 32, wc = (w & 1) * 64;
  f32x4 acc[2][4] = {};
  for (int kt = 0; kt < K; kt += 64) {
#pragma unroll
    for (int i = 0; i < 2; ++i) {
      int c = (i * 4 + w) * 64 + l;
      LOADLDS16(A + (size_t)(m0 + (c >> 3)) * K + kt + (c & 7) * 8,
                As + (size_t)(i * 4 + w) * 512);
    }
#pragma unroll
    for (int i = 0; i < 4; ++i) {
      int c = (i * 4 + w) * 64 + l;
      LOADLDS16(Bt + (size_t)(n0 + (c >> 3)) * K + kt + (c & 7) * 8,
                Bs + (size_t)(i * 4 + w) * 512);
    }
    __syncthreads();
#pragma unroll
    for (int kk = 0; kk < 2; ++kk) {
      f16x8 af[2], bf[4];
#pragma unroll
      for (int m = 0; m < 2; ++m)
        af[m] = *reinterpret_cast<const f16x8*>(As + (wr + m * 16 + lr) * 64 + kk * 32 + lq * 8);
#pragma unroll
      for (int n = 0; n < 4; ++n)
        bf[n] = *reinterpret_cast<const f16x8*>(Bs + (wc + n * 16 + lr) * 64 + kk * 32 + lq * 8);
#pragma unroll
      for (int m = 0; m < 2; ++m)
#pragma unroll
        for (int n = 0; n < 4; ++n)
          acc[m][n] = __builtin_amdgcn_mfma_f32_16x16x32_f16(af[m], bf[n], acc[m][n], 0, 0, 0);
    }
    __syncthreads();
  }
#pragma unroll
  for (int m = 0; m < 2; ++m)
#pragma unroll
    for (int n = 0; n < 4; ++n)
#pragma unroll
      for (int r = 0; r < 4; ++r) {
        int row = m0 + wr + m * 16 + lq * 4 + r;
        int col = n0 + wc + n * 16 + lr;
        out[(size_t)row * N + col] = acc[m][n][r];
      }
}

// ---------------------------------------------------------------------------
// V transpose per head: vb[bh][1024][64] -> vtb[bh][64][1024]
// ---------------------------------------------------------------------------
__global__ __launch_bounds__(256) void k_vtrans(const f16* __restrict__ vb,
                                                f16* __restrict__ vtb) {
  const int bh = blockIdx.y, s0 = blockIdx.x * 64;
  __shared__ f16 T[64][72];
  const int tid = threadIdx.x;
  const f16* src = vb + (size_t)bh * 1024 * 64;
#pragma unroll
  for (int i = 0; i < 2; ++i) {
    int c = i * 256 + tid;
    int row = c >> 3, co = (c & 7) * 8;
    f16x8 v = *reinterpret_cast<const f16x8*>(src + (size_t)(s0 + row) * 64 + co);
#pragma unroll
    for (int j = 0; j < 8; ++j) T[co + j][row] = v[j];
  }
  __syncthreads();
  f16* dst = vtb + (size_t)bh * 64 * 1024;
#pragma unroll
  for (int i = 0; i < 2; ++i) {
    int c = i * 256 + tid;
    int dh = c >> 3, so = (c & 7) * 8;
    f16x8 v;
#pragma unroll
    for (int j = 0; j < 8; ++j) v[j] = T[dh][so + j];
    *reinterpret_cast<f16x8*>(dst + (size_t)dh * 1024 + s0 + so) = v;
  }
}

// ---------------------------------------------------------------------------
// Fused flash attention (T5: scores = QK^T + bias, no 1/sqrt scale).
// v7: SWAPPED-OPERAND QK^T (S^T = mfma(K, Q, bias)):
//  - bias is the MFMA C-initializer, read as 2x ds_read_b128 (vec f32x4)
//  - each lane's 8 S values belong to ONE q-row (q=lr): scalar mrun/rsum,
//    per-lane defer-max check, vectorized P spill (2x ds_write_b64)
//  - PV consumes P[q=lr][kv=lq*8..+7] via 1x ds_read_b128; O layout unchanged
// DMA 2-phase staging + defer-max kept from rounds 5/6.
// LDS-pipe issues/tile: 25 -> 13.
// ---------------------------------------------------------------------------
__global__ __launch_bounds__(256) void k_attn(const f16* __restrict__ qb,
                                              const f16* __restrict__ kb,
                                              const f16* __restrict__ vtb,
                                              const float* __restrict__ bias,
                                              f16* __restrict__ ctx) {
  const int bid = blockIdx.x;
  const int ord = (bid & 7) * 128 + (bid >> 3);
  const int h = ord >> 6, qt = (ord >> 2) & 15, b = ord & 3;
  const int bh = b * 16 + h;
  const int q0 = qt * 64;
  const int tid = threadIdx.x, w = tid >> 6, l = tid & 63;
  const int lr = l & 15, lq = l >> 4;

  __shared__ f16 Kb[2][2048];    // [kv=32][dh=64], granule-swizzled
  __shared__ f16 Vb[2][2048];    // [dh=64][kv=32], granule-swizzled
  __shared__ float Bbf[2][2048]; // [q=64][kv=32], granule-swizzled g^(row&7)
  __shared__ f16 Ps[4][640];     // per-wave [q=16][kv pad 40]

  // Q B-fragment: Q[q=w*16+lr][dh=lq*8 (+32)]
  const f16* qp = qb + ((size_t)bh * 1024 + q0 + w * 16 + lr) * 64 + lq * 8;
  f16x8 qf0 = *reinterpret_cast<const f16x8*>(qp);
  f16x8 qf1 = *reinterpret_cast<const f16x8*>(qp + 32);

  f32x4 O[4] = {};
  float mrun = -3.0e38f, rsum = 0.f;  // per-lane; q-row = lr

  const f16* kbase = kb + (size_t)bh * 1024 * 64;
  const f16* vbase = vtb + (size_t)bh * 64 * 1024;
  const float* bbase = bias + ((size_t)h * 1024 + q0) * 1024;

  // per-lane staging geometry (wave-uniform LDS bases; per-lane global src)
  const int krow = w * 8 + (l >> 3);          // K tile row (kv)
  const int kg = (l & 7) ^ (l >> 3);          // pre-swizzled dh granule
  const int vrow = w * 16 + (l >> 2);         // V tile row (dh)
  const int vg = (l & 3) ^ ((l >> 3) & 3);    // pre-swizzled kv granule
  const int brow = w * 16 + (l >> 3);         // bias rows (2 chunks of 8)
  const int bgs = (l & 7) ^ ((l >> 3) & 7);   // pre-swizzled bias granule

  auto stage = [&](int t, int nxt) {
    LOADLDS16(kbase + (size_t)(t * 32 + krow) * 64 + kg * 8, &Kb[nxt][w * 512]);
    LOADLDS16(vbase + (size_t)vrow * 1024 + t * 32 + vg * 8, &Vb[nxt][w * 512]);
    LOADLDS16(bbase + (size_t)brow * 1024 + t * 32 + bgs * 4, &Bbf[nxt][w * 512]);
    LOADLDS16(bbase + (size_t)(brow + 8) * 1024 + t * 32 + bgs * 4,
              &Bbf[nxt][w * 512 + 256]);
  };

  // ---- prologue: stage tile 0 (syncthreads drains vmcnt) ----
  stage(0, 0);
  __syncthreads();

#pragma unroll 1
  for (int t = 0; t < 32; ++t) {
    const int cur = t & 1;
    // ---- issue next tile's DMA (in-flight across the whole body) ----
    if (t < 31) stage(t + 1, cur ^ 1);
    __builtin_amdgcn_sched_barrier(0);

    // ---- S^T init = bias (vectorized b128: 4 consecutive kv per lane) ----
    f32x4 S[2];
#pragma unroll
    for (int c = 0; c < 2; ++c) {
      int G = c * 4 + lq;
      S[c] = *reinterpret_cast<const f32x4*>(
          &Bbf[cur][(w * 16 + lr) * 32 + ((G ^ (lr & 7)) << 2)]);
    }

    // ---- S^T += K Q^T  (rows kv = c*16+lq*4+r, cols q = w*16+lr) ----
    __builtin_amdgcn_s_setprio(1);
#pragma unroll
    for (int c = 0; c < 2; ++c) {
      int row = c * 16 + lr;
      const f16* kbp = &Kb[cur][row * 64];
      f16x8 kf0 = *reinterpret_cast<const f16x8*>(kbp + ((lq ^ (lr & 7)) * 8));
      f16x8 kf1 = *reinterpret_cast<const f16x8*>(kbp + (((4 + lq) ^ (lr & 7)) * 8));
      S[c] = __builtin_amdgcn_mfma_f32_16x16x32_f16(kf0, qf0, S[c], 0, 0, 0);
      S[c] = __builtin_amdgcn_mfma_f32_16x16x32_f16(kf1, qf1, S[c], 0, 0, 0);
    }
    __builtin_amdgcn_s_setprio(0);

    // ---- defer-max: per-lane bound check (all 8 vals are q=lr) ----
    float tmax = fmaxf(fmaxf(fmaxf(S[0][0], S[0][1]), fmaxf(S[0][2], S[0][3])),
                       fmaxf(fmaxf(S[1][0], S[1][1]), fmaxf(S[1][2], S[1][3])));
    if (!__all(tmax <= mrun + 8.0f)) {
      // rare: reduce max across the 4 lq replicas, rescale O/rsum
      tmax = fmaxf(tmax, __shfl_xor(tmax, 16, 64));
      tmax = fmaxf(tmax, __shfl_xor(tmax, 32, 64));
      float mnew = fmaxf(mrun, tmax);
      float sc = __expf(mrun - mnew);
      mrun = mnew;
      rsum *= sc;
      int sb = l & 48;
#pragma unroll
      for (int r = 0; r < 4; ++r) {
        float scO = __shfl(sc, sb | (lq * 4 + r), 64);
#pragma unroll
        for (int c = 0; c < 4; ++c) O[c][r] *= scO;
      }
    }

    // ---- P = exp(S - mrun); scalar rsum; vectorized spill (b64 x2) ----
#pragma unroll
    for (int c = 0; c < 2; ++c) {
      f32x4 p;
#pragma unroll
      for (int r = 0; r < 4; ++r) p[r] = __expf(S[c][r] - mrun);
      rsum += (p[0] + p[1]) + (p[2] + p[3]);
      f16x4 ph = {(f16)p[0], (f16)p[1], (f16)p[2], (f16)p[3]};
      *reinterpret_cast<f16x4*>(&Ps[w][lr * 40 + c * 16 + lq * 4]) = ph;
    }

    // ---- O += P @ V (wave-private Ps; lgkmcnt orders round-trip) ----
    {
      f16x8 pa = *reinterpret_cast<const f16x8*>(&Ps[w][lr * 40 + lq * 8]);
      __builtin_amdgcn_s_setprio(1);
#pragma unroll
      for (int c = 0; c < 4; ++c) {
        int row = c * 16 + lr;
        f16x8 vf = *reinterpret_cast<const f16x8*>(
            &Vb[cur][row * 32 + ((lq ^ ((lr >> 1) & 3)) * 8)]);
        O[c] = __builtin_amdgcn_mfma_f32_16x16x32_f16(pa, vf, O[c], 0, 0, 0);
      }
      __builtin_amdgcn_s_setprio(0);
    }

    __syncthreads();
  }

  // ---- deferred sum reduction across the 4 lq replicas ----
  rsum += __shfl_xor(rsum, 16, 64);
  rsum += __shfl_xor(rsum, 32, 64);
  int sb = l & 48;
  float rs[4];
#pragma unroll
  for (int r = 0; r < 4; ++r) rs[r] = __shfl(rsum, sb | (lq * 4 + r), 64);

  // ---- epilogue: ctx[b][q][h*64+dh] f16 (O: q=lq*4+r, dh=c*16+lr) ----
#pragma unroll
  for (int c = 0; c < 4; ++c)
#pragma unroll
    for (int r = 0; r < 4; ++r) {
      float o = O[c][r] / rs[r];
      int row = q0 + w * 16 + lq * 4 + r;
      ctx[((size_t)b * 1024 + row) * 1024 + h * 64 + c * 16 + lr] = (f16)o;
    }
}

// ---------------------------------------------------------------------------
extern "C" void kernel_launch(void* const* d_in, const int* in_sizes, int n_in,
                              void* d_out, int out_size, void* d_ws,
                              size_t ws_size, hipStream_t stream) {
  const float* input_ids = (const float*)d_in[0];
  const float* enc = (const float*)d_in[1];
  const float* bias = (const float*)d_in[2];
  const float* Wq = (const float*)d_in[3];
  const float* Wk = (const float*)d_in[4];
  const float* Wv = (const float*)d_in[5];
  const float* Wo = (const float*)d_in[6];

  char* ws = (char*)d_ws;
  const size_t MB = 1024 * 1024;
  f16* Xq  = (f16*)(ws + 0 * MB);   // 8 MB; dead after QKV-proj -> reused as ctx
  f16* Xkv = (f16*)(ws + 8 * MB);   // 8 MB; dead after QKV-proj -> reused as vtb
  f16* Wqt = (f16*)(ws + 16 * MB);  // 2 MB each; Wqt|Wkt|Wvt contiguous = [3072][1024]
  f16* Wkt = (f16*)(ws + 18 * MB);
  f16* Wvt = (f16*)(ws + 20 * MB);
  f16* Wot = (f16*)(ws + 22 * MB);
  f16* qbuf = (f16*)(ws + 24 * MB); // 8 MB [bh][s][dh]; kbuf/vbuf planes follow
  f16* kbuf = (f16*)(ws + 32 * MB);
  f16* vbuf = (f16*)(ws + 40 * MB);
  f16* vtb = Xkv;   // [bh][dh][sk]
  f16* ctxb = Xq;   // [4096][1024]

  k_cast2<<<8192, 256, 0, stream>>>(input_ids, enc, Xq, Xkv);
  k_castw_t<<<dim3(16, 16, 4), 256, 0, stream>>>(Wq, Wk, Wv, Wo, Wqt, Wkt, Wvt, Wot);

  // fused Q+K+V projection: N=3072 over [Wqt|Wkt|Wvt], per-block A select
  k_gemm_qkv<<<dim3(24, 32), 256, 0, stream>>>(Xq, Xkv, Wqt, qbuf);

  k_vtrans<<<dim3(16, 64), 256, 0, stream>>>(vbuf, vtb);

  k_attn<<<1024, 256, 0, stream>>>(qbuf, kbuf, vtb, bias, ctxb);

  k_gemm_o<<<dim3(8, 64), 256, 0, stream>>>(ctxb, Wot, (float*)d_out, 4096, 1024, 1024);
}